// Round 1
// baseline (144.165 us; speedup 1.0000x reference)
//
#include <hip/hip_runtime.h>

// Outputs (concatenated flat, all written as float32):
//   [0,   P)  distflat2
//   [P,  2P)  pair_first
//   [2P, 3P)  pair_second
//   [3P, 6P)  paircoord (row-major [P][3])
//   [6P, 9P)  offsets   (row-major [P][3])
//   [9P,10P)  offset_index
__global__ void _DispatchNeighbors_61787399520646_kernel(
    const float* __restrict__ coordinates,    // [n_flat, 3]
    const float* __restrict__ cell,           // [n_mol, 3, 3]
    const int*   __restrict__ real_atoms,     // [n_flat]
    const int*   __restrict__ inv_real_atoms, // [n_flat]
    const int*   __restrict__ mol_index,      // [n_flat]
    const int*   __restrict__ pair_first_raw, // [P]
    const int*   __restrict__ pair_second_raw,// [P]
    const int*   __restrict__ offsets,        // [P, 3]
    const int*   __restrict__ n_images_p,     // scalar
    float* __restrict__ out,
    int P)
{
    const int n_images = n_images_p[0];
    const int n_off = 2 * n_images + 1;

    int p = blockIdx.x * blockDim.x + threadIdx.x;
    if (p >= P) return;

    // index maps (identity in this dataset, but apply them per the reference)
    const int pf = inv_real_atoms[pair_first_raw[p]];
    const int ps = inv_real_atoms[pair_second_raw[p]];

    // per-pair periodic image offset
    const int o0 = offsets[3 * p + 0];
    const int o1 = offsets[3 * p + 1];
    const int o2 = offsets[3 * p + 2];

    // cell gather: pair_mol = mol_index[pair_first]; pair_cell = cell[pair_mol]
    const int mol = mol_index[pf];
    const float* __restrict__ C = cell + mol * 9;

    const float f0 = (float)o0, f1 = (float)o1, f2 = (float)o2;
    // einsum('pi,pij->pj'): po[j] = sum_i off[i] * C[i][j]
    const float po0 = f0 * C[0] + f1 * C[3] + f2 * C[6];
    const float po1 = f0 * C[1] + f1 * C[4] + f2 * C[7];
    const float po2 = f0 * C[2] + f1 * C[5] + f2 * C[8];

    // coordinate gathers through real_atoms map
    const int ra = real_atoms[pf];
    const int rb = real_atoms[ps];
    const float ax = coordinates[3 * ra + 0];
    const float ay = coordinates[3 * ra + 1];
    const float az = coordinates[3 * ra + 2];
    const float bx = coordinates[3 * rb + 0];
    const float by = coordinates[3 * rb + 1];
    const float bz = coordinates[3 * rb + 2];

    const float pcx = ax - bx + po0;
    const float pcy = ay - by + po1;
    const float pcz = az - bz + po2;

    const float dist = sqrtf(pcx * pcx + pcy * pcy + pcz * pcz);

    out[p]               = dist;
    out[P + p]           = (float)pf;
    out[2 * P + p]       = (float)ps;

    const int b3 = 3 * P + 3 * p;
    out[b3 + 0] = pcx;
    out[b3 + 1] = pcy;
    out[b3 + 2] = pcz;

    const int b6 = 6 * P + 3 * p;
    out[b6 + 0] = (float)o0;
    out[b6 + 1] = (float)o1;
    out[b6 + 2] = (float)o2;

    const int oi = (o2 + n_images) + n_off * ((o1 + n_images) + n_off * (o0 + n_images));
    out[9 * P + p] = (float)oi;
}

extern "C" void kernel_launch(void* const* d_in, const int* in_sizes, int n_in,
                              void* d_out, int out_size, void* d_ws, size_t ws_size,
                              hipStream_t stream) {
    const float* coordinates     = (const float*)d_in[0];
    const float* cell            = (const float*)d_in[1];
    const int*   real_atoms      = (const int*)d_in[2];
    const int*   inv_real_atoms  = (const int*)d_in[3];
    const int*   mol_index       = (const int*)d_in[4];
    const int*   pair_first_raw  = (const int*)d_in[5];
    const int*   pair_second_raw = (const int*)d_in[6];
    const int*   offsets         = (const int*)d_in[7];
    const int*   n_images_p      = (const int*)d_in[8];

    const int P = in_sizes[5];  // number of pairs
    float* out = (float*)d_out;

    const int block = 256;
    const int grid = (P + block - 1) / block;
    _DispatchNeighbors_61787399520646_kernel<<<grid, block, 0, stream>>>(
        coordinates, cell, real_atoms, inv_real_atoms, mol_index,
        pair_first_raw, pair_second_raw, offsets, n_images_p, out, P);
}